// Round 5
// baseline (243.261 us; speedup 1.0000x reference)
//
#include <hip/hip_runtime.h>
#include <stdint.h>

#define F_IN 65536
#define NN 100
#define CO 60
#define G_SPLIT 256
#define KC (F_IN/G_SPLIT)   // 256
#define BK 32
#define NIT (KC/BK)         // 8

typedef short v8s __attribute__((ext_vector_type(8)));
typedef float v4f __attribute__((ext_vector_type(4)));

__device__ __forceinline__ unsigned int f2bf(float x){
  unsigned int u = __float_as_uint(x);
  u += 0x7fffu + ((u>>16)&1u);      // round-to-nearest-even
  return u>>16;
}
__device__ __forceinline__ v4f mfma16(v8s a, v8s b, v4f c){
  return __builtin_amdgcn_mfma_f32_16x16x32_bf16(a,b,c,0,0,0);
}

// ---------------------------------------------------------------------------
// K0: x (f32) -> xb (bf16), once.  Amortized over the 6 GEMM reads of x.
// ---------------------------------------------------------------------------
__global__ __launch_bounds__(256)
void k_cvt(const float* __restrict__ x, unsigned short* __restrict__ xb){
  int i = blockIdx.x*256 + threadIdx.x;           // 6400*256*4 == 6,553,600 exactly
  float4 v = ((const float4*)x)[i];
  uint2 w;
  w.x = f2bf(v.x) | (f2bf(v.y)<<16);
  w.y = f2bf(v.z) | (f2bf(v.w)<<16);
  ((uint2*)xb)[i] = w;
}

// ---------------------------------------------------------------------------
// K1: split-K GEMM, NO LDS / NO BARRIERS.  grid=(G_SPLIT,6), 1536 blocks.
// Each wave: 16-col group of one matrix g; A-fragments loaded straight from
// bf16 x with global_load_dwordx4 (the 16B MFMA A-frag IS contiguous memory);
// B-fragments: 8 strided f32 loads + cvt.  Stalls are per-wave (no barrier
// coupling) and hidden by 16 waves/CU; A-tile reuse across the block's 4
// waves is served by L1 (7 KB/iter), W comes from L2/L3.
// Epilogue: plain stores to P[g][s][6000]; k_reduce folds 256 slices.
// ---------------------------------------------------------------------------
__global__ __launch_bounds__(256,4)
void k_gemm(const unsigned short* __restrict__ xb, const float* __restrict__ aw,
            const float* __restrict__ cw, float* __restrict__ dst, int partial){
  const int s = blockIdx.x, g = blockIdx.y;
  const int k0 = s*KC;
  const int tid = threadIdx.x, wave = tid>>6, lane = tid&63, quad = lane>>4, nl = lane&15;
  const int c0 = wave*16, ccl = min(c0+nl, CO-1);   // clamp pad cols; discarded at store

  const float* Wm = (g<3) ? (aw + (size_t)g*F_IN*CO) : (cw + (size_t)(g-3)*F_IN*CO);
  const float* wp = Wm + (size_t)(k0 + quad*8)*CO + ccl;   // per-lane column base

  // per-m-tile A base pointers (k0 + quad*8 folded in; only it*BK varies)
  const unsigned short* ap[7];
  #pragma unroll
  for(int mt=0;mt<7;++mt){
    int r = mt*16 + nl;
    int rcl = min(r, NN-1);                 // rows 100..111 clone row 99 (discarded)
    ap[mt] = xb + (size_t)rcl*F_IN + k0 + quad*8;
  }

  v4f acc[7];
  #pragma unroll
  for(int i=0;i<7;++i){ v4f z={0.f,0.f,0.f,0.f}; acc[i]=z; }

  for(int it=0; it<NIT; ++it){
    const int kk = it*BK;
    // A fragments: one dwordx4 each, already MFMA-ready bf16
    v8s a0 = *(const v8s*)(ap[0] + kk);
    v8s a1 = *(const v8s*)(ap[1] + kk);
    v8s a2 = *(const v8s*)(ap[2] + kk);
    v8s a3 = *(const v8s*)(ap[3] + kk);
    v8s a4 = *(const v8s*)(ap[4] + kk);
    v8s a5 = *(const v8s*)(ap[5] + kk);
    v8s a6 = *(const v8s*)(ap[6] + kk);
    // B fragment: 8 strided f32 loads (stride 60 floats), cvt to bf16
    float w0 = wp[(kk+0)*CO], w1 = wp[(kk+1)*CO], w2 = wp[(kk+2)*CO], w3 = wp[(kk+3)*CO];
    float w4 = wp[(kk+4)*CO], w5 = wp[(kk+5)*CO], w6 = wp[(kk+6)*CO], w7 = wp[(kk+7)*CO];
    v8s fB;
    fB[0]=(short)f2bf(w0); fB[1]=(short)f2bf(w1); fB[2]=(short)f2bf(w2); fB[3]=(short)f2bf(w3);
    fB[4]=(short)f2bf(w4); fB[5]=(short)f2bf(w5); fB[6]=(short)f2bf(w6); fB[7]=(short)f2bf(w7);
    acc[0] = mfma16(a0, fB, acc[0]);
    acc[1] = mfma16(a1, fB, acc[1]);
    acc[2] = mfma16(a2, fB, acc[2]);
    acc[3] = mfma16(a3, fB, acc[3]);
    acc[4] = mfma16(a4, fB, acc[4]);
    acc[5] = mfma16(a5, fB, acc[5]);
    acc[6] = mfma16(a6, fB, acc[6]);
  }

  // --- epilogue.  C/D layout: col=lane&15, row=quad*4+i ---
  const int c = c0 + nl;
  if(c < CO){
    if(partial){
      float* pd = dst + ((size_t)g*G_SPLIT + s)*(NN*CO);
      #pragma unroll
      for(int mt=0;mt<7;++mt){
        #pragma unroll
        for(int i=0;i<4;++i){
          int m = mt*16 + quad*4 + i;
          if(m < NN) pd[m*CO + c] = acc[mt][i];
        }
      }
    } else {
      float* pd = dst + (size_t)g*(NN*CO);
      #pragma unroll
      for(int mt=0;mt<7;++mt){
        #pragma unroll
        for(int i=0;i<4;++i){
          int m = mt*16 + quad*4 + i;
          if(m < NN) atomicAdd(pd + m*CO + c, acc[mt][i]);
        }
      }
    }
  }
}

// ---------------------------------------------------------------------------
// K1b: split-K reduce.  grid=(141,8); block (b,q) sums 32 slices of P into Y
// via atomicAdd (Y zeroed by memset).  Reads coalesced (stride 6000 floats).
// ---------------------------------------------------------------------------
__global__ void k_reduce(const float* __restrict__ P, float* __restrict__ Y){
  int o = blockIdx.x*256 + threadIdx.x;
  if(o >= 6*NN*CO) return;
  int gg = o/(NN*CO), r = o - gg*(NN*CO);
  const float* p = P + (size_t)gg*G_SPLIT*(NN*CO) + (size_t)blockIdx.y*32*(NN*CO) + r;
  float a0=0.f,a1=0.f,a2=0.f,a3=0.f;
  #pragma unroll 2
  for(int s4=0;s4<32;s4+=4){
    a0 += p[(s4  )*(NN*CO)];
    a1 += p[(s4+1)*(NN*CO)];
    a2 += p[(s4+2)*(NN*CO)];
    a3 += p[(s4+3)*(NN*CO)];
  }
  atomicAdd(&Y[o], (a0+a1)+(a2+a3));
}

// ---------------------------------------------------------------------------
// K2: cheb combine.  out = Y0 - Y2 + L@(Y1 + 2*L@Y2) + b, then tanh.
// ---------------------------------------------------------------------------
__global__ void k_cheb(const float* __restrict__ Y, const int* __restrict__ ei,
                       const float* __restrict__ ab, const float* __restrict__ cb,
                       float* __restrict__ emb){
  const int net = blockIdx.x / CO;
  const int c   = blockIdx.x % CO;
  const int t   = threadIdx.x;       // 128
  __shared__ float L[NN][NN+1];
  __shared__ float dis[NN];
  __shared__ int   deg[NN];
  __shared__ float y0[NN], y1[NN], y2[NN], zu[NN];

  for(int i=t;i<NN*(NN+1);i+=128) ((float*)L)[i]=0.f;
  if(t<NN) deg[t]=0;
  __syncthreads();
  for(int e=t;e<2000;e+=128) atomicAdd(&deg[ei[e]],1);
  __syncthreads();
  if(t<NN) dis[t] = deg[t]>0 ? rsqrtf((float)deg[t]) : 0.f;
  __syncthreads();
  for(int e=t;e<2000;e+=128){
    int s = ei[e], d = ei[2000+e];
    atomicAdd(&L[d][s], -dis[s]*dis[d]);
  }
  if(t<NN){
    const float* yb = Y + (size_t)net*3*NN*CO + t*CO + c;
    y0[t]=yb[0]; y1[t]=yb[NN*CO]; y2[t]=yb[2*NN*CO];
  }
  __syncthreads();
  if(t<NN){
    float s=0.f;
    #pragma unroll 4
    for(int j=0;j<NN;++j) s += L[t][j]*y2[j];
    zu[t] = y1[t] + 2.f*s;
  }
  __syncthreads();
  if(t<NN){
    float s=0.f;
    #pragma unroll 4
    for(int j=0;j<NN;++j) s += L[t][j]*zu[j];
    float b = (net==0) ? ab[c] : cb[c];
    emb[net*NN*CO + t*CO + c] = tanhf(y0[t] - y2[t] + s + b);
  }
}

// ---------------------------------------------------------------------------
// K3: final FC.  out zeroed by memset.  Blocks 0..24: coalesced logits
// partials; block 25: value dot + biases + scalar extras.
// ---------------------------------------------------------------------------
#define FCB 25
__global__ void k_fc(const float* __restrict__ emb, const float* __restrict__ afw,
                     const float* __restrict__ afb, const float* __restrict__ cfw,
                     const float* __restrict__ cfb, const float* __restrict__ s0,
                     const float* __restrict__ s1, const float* __restrict__ s2,
                     float* __restrict__ out){
  const int b = blockIdx.x;
  const int t = threadIdx.x;         // 256
  if(b < FCB){
    const int jj = t & 127, half = t >> 7;
    if(jj < 100){
      const int i0 = b*240 + half*120;
      const float* w = afw + (size_t)i0*100 + jj;
      const float* e = emb + i0;
      float p = 0.f;
      #pragma unroll 4
      for(int i=0;i<120;++i) p += e[i]*w[(size_t)i*100];
      atomicAdd(&out[jj], p);
    }
  } else {
    float p = 0.f;
    const float* e = emb + 6000;
    for(int i=t;i<6000;i+=256) p += e[i]*cfw[i];
    #pragma unroll
    for(int o=32;o>0;o>>=1) p += __shfl_down(p,o,64);
    __shared__ float red[4];
    if((t&63)==0) red[t>>6]=p;
    __syncthreads();
    if(t==0){
      float tot = red[0]+red[1]+red[2]+red[3];
      out[100] = tot + s0[0]*cfw[6000] + s1[0]*cfw[6001] + s2[0]*cfw[6002] + cfb[0];
    }
    if(t<100){
      atomicAdd(&out[t], afb[t] + s0[0]*afw[600000+t] + s1[0]*afw[600100+t] + s2[0]*afw[600200+t]);
    }
  }
}

extern "C" void kernel_launch(void* const* d_in, const int* in_sizes, int n_in,
                              void* d_out, int out_size, void* d_ws, size_t ws_size,
                              hipStream_t stream){
  const float* x   = (const float*)d_in[0];
  const int*   ei  = (const int*)d_in[1];
  const float* s0  = (const float*)d_in[2];
  const float* s1  = (const float*)d_in[3];
  const float* s2  = (const float*)d_in[4];
  const float* aw  = (const float*)d_in[5];
  const float* ab  = (const float*)d_in[6];
  const float* cw  = (const float*)d_in[7];
  const float* cb  = (const float*)d_in[8];
  const float* afw = (const float*)d_in[9];
  const float* afb = (const float*)d_in[10];
  const float* cfw = (const float*)d_in[11];
  const float* cfb = (const float*)d_in[12];
  float* out = (float*)d_out;

  // ws layout: xb (13,107,200 B) | Y (144,000 B) | emb (48,000 B) | P (36,864,000 B)
  unsigned short* xb = (unsigned short*)d_ws;
  float* Y   = (float*)((char*)d_ws + 13107200);
  float* emb = Y + 6*NN*CO;
  float* P   = emb + 2*NN*CO;
  const size_t need_full = 13107200u + (size_t)(6*NN*CO + 2*NN*CO)*4
                         + (size_t)6*G_SPLIT*NN*CO*4;
  const int partial = (ws_size >= need_full) ? 1 : 0;

  hipMemsetAsync(Y, 0, 6*NN*CO*sizeof(float), stream);
  hipMemsetAsync(out, 0, 101*sizeof(float), stream);

  k_cvt<<<6400, 256, 0, stream>>>(x, xb);
  k_gemm<<<dim3(G_SPLIT,6), 256, 0, stream>>>(xb, aw, cw, partial ? P : Y, partial);
  if(partial){
    k_reduce<<<dim3((6*NN*CO+255)/256, 8), 256, 0, stream>>>(P, Y);
  }
  k_cheb<<<120, 128, 0, stream>>>(Y, ei, ab, cb, emb);
  k_fc<<<FCB+1, 256, 0, stream>>>(emb, afw, afb, cfw, cfb, s0, s1, s2, out);
}

// Round 7
// 223.376 us; speedup vs baseline: 1.0890x; 1.0890x over previous
//
#include <hip/hip_runtime.h>
#include <stdint.h>

#define F_IN 65536
#define NN 100
#define CO 60
#define G_SPLIT 256
#define KC (F_IN/G_SPLIT)   // 256
#define BK 32
#define NIT (KC/BK)         // 8
#define AROW 264            // LDS A row stride in shorts (528 B = 33*16: b128-aligned, 2-way alias only)

typedef short v8s __attribute__((ext_vector_type(8)));
typedef float v4f __attribute__((ext_vector_type(4)));

__device__ __forceinline__ unsigned int f2bf(float x){
  unsigned int u = __float_as_uint(x);
  u += 0x7fffu + ((u>>16)&1u);      // round-to-nearest-even
  return u>>16;
}
__device__ __forceinline__ v4f mfma16(v8s a, v8s b, v4f c){
  return __builtin_amdgcn_mfma_f32_16x16x32_bf16(a,b,c,0,0,0);
}

// ---------------------------------------------------------------------------
// K1: split-K GEMM.  grid=(G_SPLIT,6)=1536 blocks, 2/CU (LDS 59KB), 3 rounds.
// A: whole 112x256 bf16 slab staged ONCE into LDS (fused f32->bf16), one
// barrier total; K-loop reads A-frags via ds_read_b128 (lgkm only).
// B: the ONLY in-loop vector-memory ops are 8 global_load_dword per iter
// inside opaque inline asm (earlyclobber outs, manual `s_waitcnt vmcnt(8)`
// with dataflow ties) -> compiler cannot sink, serialize, or over-wait them.
// Distance-1 double-banked prefetch, per-wave; no in-loop barriers at all.
// ---------------------------------------------------------------------------
#define LOADB(BNK_, ITN_) \
  asm volatile( \
    "global_load_dword %0, %8, %9\n\t" \
    "global_load_dword %1, %8, %9 offset:240\n\t" \
    "global_load_dword %2, %8, %9 offset:480\n\t" \
    "global_load_dword %3, %8, %9 offset:720\n\t" \
    "global_load_dword %4, %8, %9 offset:960\n\t" \
    "global_load_dword %5, %8, %9 offset:1200\n\t" \
    "global_load_dword %6, %8, %9 offset:1440\n\t" \
    "global_load_dword %7, %8, %9 offset:1680\n\t" \
    : "=&v"(Bb[(BNK_)][0]), "=&v"(Bb[(BNK_)][1]), "=&v"(Bb[(BNK_)][2]), \
      "=&v"(Bb[(BNK_)][3]), "=&v"(Bb[(BNK_)][4]), "=&v"(Bb[(BNK_)][5]), \
      "=&v"(Bb[(BNK_)][6]), "=&v"(Bb[(BNK_)][7]) \
    : "v"(wo + (ITN_)*7680u), "s"(Wm) \
    : )

#define WAITB(BNK_, CNT_) \
  asm volatile("s_waitcnt vmcnt(" CNT_ ")" \
    : "+v"(Bb[(BNK_)][0]), "+v"(Bb[(BNK_)][1]), "+v"(Bb[(BNK_)][2]), \
      "+v"(Bb[(BNK_)][3]), "+v"(Bb[(BNK_)][4]), "+v"(Bb[(BNK_)][5]), \
      "+v"(Bb[(BNK_)][6]), "+v"(Bb[(BNK_)][7]) :: )

__global__ __launch_bounds__(256,2)
void k_gemm(const float* __restrict__ x, const float* __restrict__ aw,
            const float* __restrict__ cw, float* __restrict__ dst, int partial){
  const int s = blockIdx.x, g = blockIdx.y;
  const int k0 = s*KC;
  const int tid = threadIdx.x, wave = tid>>6, lane = tid&63, quad = lane>>4, nl = lane&15;
  const int c0 = wave*16, ccl = min(c0+nl, CO-1);   // clamp pad cols; discarded at store

  const float* Wm = (g<3) ? (aw + (size_t)g*F_IN*CO) : (cw + (size_t)(g-3)*F_IN*CO);
  const unsigned int wo = (unsigned)(((k0 + quad*8)*CO + ccl)*4);

  __shared__ __align__(16) unsigned short As[112*AROW];   // 59,136 B

  // --- stage A slab once: f32 x -> bf16 LDS (112 rows x 256 k) ---
  #pragma unroll
  for(int p=0;p<28;++p){
    int lin = p*256 + tid;
    int row = lin>>6, ch = lin&63;          // 64 x (4-float) chunks per row
    int rcl = min(row, NN-1);               // rows 100..111 clone row 99 (discarded)
    float4 v = *(const float4*)(x + (size_t)rcl*F_IN + k0 + ch*4);
    uint2 w;
    w.x = f2bf(v.x) | (f2bf(v.y)<<16);
    w.y = f2bf(v.z) | (f2bf(v.w)<<16);
    *(uint2*)((char*)As + row*528 + ch*8) = w;
  }
  __syncthreads();                          // the ONLY barrier

  float Bb[2][8];
  v4f acc[7];
  #pragma unroll
  for(int i=0;i<7;++i){ v4f z={0.f,0.f,0.f,0.f}; acc[i]=z; }

  LOADB(0, 0);                              // prime bank 0

  const char* Abase = (const char*)As + nl*528 + quad*16;

  #pragma unroll
  for(int it=0; it<NIT; ++it){
    if(it+1 < NIT){
      LOADB((it+1)&1, it+1);
      WAITB(it&1, "8");                     // my iter-it batch landed
    } else {
      WAITB(it&1, "0");
    }
    const int bk = it&1;
    v8s fB;
    #pragma unroll
    for(int j=0;j<8;++j) fB[j] = (short)f2bf(Bb[bk][j]);
    #pragma unroll
    for(int mt=0;mt<7;++mt){
      v8s a = *(const v8s*)(Abase + mt*8448 + it*64);   // ds_read_b128, imm offsets
      acc[mt] = mfma16(a, fB, acc[mt]);
    }
  }

  // --- epilogue.  C/D layout: col=lane&15, row=quad*4+i ---
  const int c = c0 + nl;
  if(c < CO){
    if(partial){
      float* pd = dst + ((size_t)g*G_SPLIT + s)*(NN*CO);
      #pragma unroll
      for(int mt=0;mt<7;++mt){
        #pragma unroll
        for(int i=0;i<4;++i){
          int m = mt*16 + quad*4 + i;
          if(m < NN) pd[m*CO + c] = acc[mt][i];
        }
      }
    } else {
      float* pd = dst + (size_t)g*(NN*CO);
      #pragma unroll
      for(int mt=0;mt<7;++mt){
        #pragma unroll
        for(int i=0;i<4;++i){
          int m = mt*16 + quad*4 + i;
          if(m < NN) atomicAdd(pd + m*CO + c, acc[mt][i]);
        }
      }
    }
  }
}

// ---------------------------------------------------------------------------
// K1b: split-K reduce.  grid=(141,8); block (b,q) sums 32 slices of P into Y
// via atomicAdd (Y zeroed by memset).  Reads coalesced (stride 6000 floats).
// ---------------------------------------------------------------------------
__global__ void k_reduce(const float* __restrict__ P, float* __restrict__ Y){
  int o = blockIdx.x*256 + threadIdx.x;
  if(o >= 6*NN*CO) return;
  int gg = o/(NN*CO), r = o - gg*(NN*CO);
  const float* p = P + (size_t)gg*G_SPLIT*(NN*CO) + (size_t)blockIdx.y*32*(NN*CO) + r;
  float a0=0.f,a1=0.f,a2=0.f,a3=0.f;
  #pragma unroll 2
  for(int s4=0;s4<32;s4+=4){
    a0 += p[(s4  )*(NN*CO)];
    a1 += p[(s4+1)*(NN*CO)];
    a2 += p[(s4+2)*(NN*CO)];
    a3 += p[(s4+3)*(NN*CO)];
  }
  atomicAdd(&Y[o], (a0+a1)+(a2+a3));
}

// ---------------------------------------------------------------------------
// K2: cheb combine.  out = Y0 - Y2 + L@(Y1 + 2*L@Y2) + b, then tanh.
// ---------------------------------------------------------------------------
__global__ void k_cheb(const float* __restrict__ Y, const int* __restrict__ ei,
                       const float* __restrict__ ab, const float* __restrict__ cb,
                       float* __restrict__ emb){
  const int net = blockIdx.x / CO;
  const int c   = blockIdx.x % CO;
  const int t   = threadIdx.x;       // 128
  __shared__ float L[NN][NN+1];
  __shared__ float dis[NN];
  __shared__ int   deg[NN];
  __shared__ float y0[NN], y1[NN], y2[NN], zu[NN];

  for(int i=t;i<NN*(NN+1);i+=128) ((float*)L)[i]=0.f;
  if(t<NN) deg[t]=0;
  __syncthreads();
  for(int e=t;e<2000;e+=128) atomicAdd(&deg[ei[e]],1);
  __syncthreads();
  if(t<NN) dis[t] = deg[t]>0 ? rsqrtf((float)deg[t]) : 0.f;
  __syncthreads();
  for(int e=t;e<2000;e+=128){
    int s = ei[e], d = ei[2000+e];
    atomicAdd(&L[d][s], -dis[s]*dis[d]);
  }
  if(t<NN){
    const float* yb = Y + (size_t)net*3*NN*CO + t*CO + c;
    y0[t]=yb[0]; y1[t]=yb[NN*CO]; y2[t]=yb[2*NN*CO];
  }
  __syncthreads();
  if(t<NN){
    float s=0.f;
    #pragma unroll 4
    for(int j=0;j<NN;++j) s += L[t][j]*y2[j];
    zu[t] = y1[t] + 2.f*s;
  }
  __syncthreads();
  if(t<NN){
    float s=0.f;
    #pragma unroll 4
    for(int j=0;j<NN;++j) s += L[t][j]*zu[j];
    float b = (net==0) ? ab[c] : cb[c];
    emb[net*NN*CO + t*CO + c] = tanhf(y0[t] - y2[t] + s + b);
  }
}

// ---------------------------------------------------------------------------
// K3: final FC.  out zeroed by memset.  Blocks 0..24: coalesced logits
// partials; block 25: value dot + biases + scalar extras.
// ---------------------------------------------------------------------------
#define FCB 25
__global__ void k_fc(const float* __restrict__ emb, const float* __restrict__ afw,
                     const float* __restrict__ afb, const float* __restrict__ cfw,
                     const float* __restrict__ cfb, const float* __restrict__ s0,
                     const float* __restrict__ s1, const float* __restrict__ s2,
                     float* __restrict__ out){
  const int b = blockIdx.x;
  const int t = threadIdx.x;         // 256
  if(b < FCB){
    const int jj = t & 127, half = t >> 7;
    if(jj < 100){
      const int i0 = b*240 + half*120;
      const float* w = afw + (size_t)i0*100 + jj;
      const float* e = emb + i0;
      float p = 0.f;
      #pragma unroll 4
      for(int i=0;i<120;++i) p += e[i]*w[(size_t)i*100];
      atomicAdd(&out[jj], p);
    }
  } else {
    float p = 0.f;
    const float* e = emb + 6000;
    for(int i=t;i<6000;i+=256) p += e[i]*cfw[i];
    #pragma unroll
    for(int o=32;o>0;o>>=1) p += __shfl_down(p,o,64);
    __shared__ float red[4];
    if((t&63)==0) red[t>>6]=p;
    __syncthreads();
    if(t==0){
      float tot = red[0]+red[1]+red[2]+red[3];
      out[100] = tot + s0[0]*cfw[6000] + s1[0]*cfw[6001] + s2[0]*cfw[6002] + cfb[0];
    }
    if(t<100){
      atomicAdd(&out[t], afb[t] + s0[0]*afw[600000+t] + s1[0]*afw[600100+t] + s2[0]*afw[600200+t]);
    }
  }
}

extern "C" void kernel_launch(void* const* d_in, const int* in_sizes, int n_in,
                              void* d_out, int out_size, void* d_ws, size_t ws_size,
                              hipStream_t stream){
  const float* x   = (const float*)d_in[0];
  const int*   ei  = (const int*)d_in[1];
  const float* s0  = (const float*)d_in[2];
  const float* s1  = (const float*)d_in[3];
  const float* s2  = (const float*)d_in[4];
  const float* aw  = (const float*)d_in[5];
  const float* ab  = (const float*)d_in[6];
  const float* cw  = (const float*)d_in[7];
  const float* cb  = (const float*)d_in[8];
  const float* afw = (const float*)d_in[9];
  const float* afb = (const float*)d_in[10];
  const float* cfw = (const float*)d_in[11];
  const float* cfb = (const float*)d_in[12];
  float* out = (float*)d_out;

  // ws layout: P [6][G_SPLIT][6000] (36,864,000 B) | Y [6][6000] | emb [2][6000]
  float* P   = (float*)d_ws;
  float* Y   = P + (size_t)6*G_SPLIT*NN*CO;
  float* emb = Y + 6*NN*CO;
  const size_t need_full = ((size_t)6*G_SPLIT*NN*CO + 6*NN*CO + 2*NN*CO)*sizeof(float);
  const int partial = (ws_size >= need_full) ? 1 : 0;

  hipMemsetAsync(Y, 0, 6*NN*CO*sizeof(float), stream);
  hipMemsetAsync(out, 0, 101*sizeof(float), stream);

  k_gemm<<<dim3(G_SPLIT,6), 256, 0, stream>>>(x, aw, cw, partial ? P : Y, partial);
  if(partial){
    k_reduce<<<dim3((6*NN*CO+255)/256, 8), 256, 0, stream>>>(P, Y);
  }
  k_cheb<<<120, 128, 0, stream>>>(Y, ei, ab, cb, emb);
  k_fc<<<FCB+1, 256, 0, stream>>>(emb, afw, afb, cfw, cfb, s0, s1, s2, out);
}